// Round 1
// baseline (10232.850 us; speedup 1.0000x reference)
//
#include <hip/hip_runtime.h>
#include <cstdint>
#include <cstddef>

typedef __attribute__((ext_vector_type(8))) short short8;
typedef __attribute__((ext_vector_type(4))) float f32x4;

#define N_SPK 64
#define M_UTT 10
#define T_SEQ 160
#define IN_F  40
#define H_DIM 256
#define B_TOT 640
#define G4    1024

__device__ __forceinline__ unsigned short f2bf(float f) {
  unsigned int u = __float_as_uint(f);
  u += 0x7FFFu + ((u >> 16) & 1u);   // round-to-nearest-even
  return (unsigned short)(u >> 16);
}
__device__ __forceinline__ float sigm(float x) {
  x = fminf(fmaxf(x, -30.f), 30.f);
  return 1.f / (1.f + __expf(-x));
}
__device__ __forceinline__ float tanh_fast(float x) {
  x = fminf(fmaxf(x, -15.f), 15.f);
  float e = __expf(2.f * x);
  return (e - 1.f) / (e + 1.f);
}

// ---------------------------------------------------------------------------
// Weight pack: B-fragment order for mfma_f32_16x16x32_bf16.
// out[((tile*Ktiles + ks)*64 + lane)*8 + j] = W[tile*16 + (lane&15)][ks*32 + (lane>>4)*8 + j]
// (zero-padded for k >= Kin). One wave's load per (tile,ks) is a contiguous 1 KB.
// ---------------------------------------------------------------------------
__global__ void pack_w_kernel(const float* __restrict__ W, short* __restrict__ out,
                              int Kin, int Ktiles) {
  int idx = blockIdx.x * 256 + threadIdx.x;
  int total = 64 * Ktiles * 64;
  if (idx >= total) return;
  int lane = idx & 63;
  int rest = idx >> 6;
  int ks   = rest % Ktiles;
  int tile = rest / Ktiles;
  int n  = tile * 16 + (lane & 15);
  int k0 = ks * 32 + (lane >> 4) * 8;
  short8 v;
#pragma unroll
  for (int j = 0; j < 8; ++j) {
    int k = k0 + j;
    float f = (k < Kin) ? W[(size_t)n * Kin + k] : 0.f;
    v[j] = (short)f2bf(f);
  }
  *(short8*)&out[(size_t)idx * 8] = v;
}

__global__ void bias_sum_kernel(const float* __restrict__ a, const float* __restrict__ b,
                                float* __restrict__ o) {
  int i = blockIdx.x * 256 + threadIdx.x;
  if (i < G4) o[i] = a[i] + b[i];
}

// ---------------------------------------------------------------------------
// Fused LSTM layer. One block = 16 samples, 4 waves, full T loop, no inter-block
// sync. Wave w owns column-tiles {tile : tile%4==w} -> complete i/f/g/o
// quadruples for its 64 h-columns; c in regs, h in LDS (bf16).
// MODE 0: x from sequences (fp32, K padded 40->64), write hseq
// MODE 1: x from hseq (in-place: block only touches its own 16 rows), write hseq
// MODE 2: x from hseq, write c_last only
// ---------------------------------------------------------------------------
template<int KPAD, int MODE>
__global__ __launch_bounds__(256)
void lstm_kernel(const float* seq, const unsigned short* hseq_in, unsigned short* hseq_out,
                 const short* __restrict__ Wih_p, const short* __restrict__ Whh_p,
                 const float* __restrict__ bias, const int* __restrict__ lens,
                 float* c_out) {
  constexpr int KT_IN = KPAD / 32;
  const int b0   = blockIdx.x * 16;
  const int tid  = threadIdx.x;
  const int lane = tid & 63;
  const int wave = tid >> 6;
  const int mq   = lane >> 4;   // quad
  const int nl   = lane & 15;

  __shared__ unsigned short x_sh[16][KPAD + 8];   // +16B row pad
  __shared__ unsigned short h_sh[16][H_DIM + 8];
  __shared__ float bias_sh[G4];
  __shared__ int len_sh[16];

  for (int i = tid; i < G4; i += 256) bias_sh[i] = bias[i];
  for (int i = tid; i < 16 * (H_DIM + 8); i += 256) (&h_sh[0][0])[i] = 0;
  if (tid < 16) len_sh[tid] = lens[b0 + tid];

  float c_reg[4][4];
#pragma unroll
  for (int a = 0; a < 4; ++a)
#pragma unroll
    for (int r = 0; r < 4; ++r) c_reg[a][r] = 0.f;

  __syncthreads();

  for (int t = 0; t < T_SEQ; ++t) {
    // ---- stage x_t into LDS ----
    if (MODE == 0) {
      for (int i = tid; i < 16 * 64; i += 256) {
        int m = i >> 6, k = i & 63;
        float v = (k < IN_F) ? seq[((size_t)(b0 + m) * T_SEQ + t) * IN_F + k] : 0.f;
        x_sh[m][k] = f2bf(v);
      }
    } else {
      const unsigned short* src = hseq_in + ((size_t)t * B_TOT + b0) * H_DIM;
      for (int i = tid; i < 512; i += 256) {
        int e = i * 8;
        int m = e >> 8, k = e & 255;
        *(short8*)&x_sh[m][k] = *(const short8*)&src[e];
      }
    }
    __syncthreads();  // x ready; h from previous step ready

    // ---- gates = bias + x@Wih^T + h@Whh^T (MFMA, fp32 accum) ----
    f32x4 acc[4][4];  // [hcj][gate]
#pragma unroll
    for (int hcj = 0; hcj < 4; ++hcj) {
      const int hc = wave + 4 * hcj;
#pragma unroll
      for (int g = 0; g < 4; ++g) {
        float bv = bias_sh[g * 256 + hc * 16 + nl];
        acc[hcj][g] = (f32x4){bv, bv, bv, bv};
      }
    }
#pragma unroll
    for (int ks = 0; ks < KT_IN; ++ks) {
      short8 a = *(const short8*)&x_sh[nl][ks * 32 + mq * 8];
#pragma unroll
      for (int hcj = 0; hcj < 4; ++hcj) {
        const int hc = wave + 4 * hcj;
#pragma unroll
        for (int g = 0; g < 4; ++g) {
          const int tile = g * 16 + hc;
          short8 b = *(const short8*)&Wih_p[((size_t)(tile * KT_IN + ks) * 64 + lane) * 8];
          acc[hcj][g] = __builtin_amdgcn_mfma_f32_16x16x32_bf16(a, b, acc[hcj][g], 0, 0, 0);
        }
      }
    }
#pragma unroll
    for (int ks = 0; ks < 8; ++ks) {
      short8 a = *(const short8*)&h_sh[nl][ks * 32 + mq * 8];
#pragma unroll
      for (int hcj = 0; hcj < 4; ++hcj) {
        const int hc = wave + 4 * hcj;
#pragma unroll
        for (int g = 0; g < 4; ++g) {
          const int tile = g * 16 + hc;
          short8 b = *(const short8*)&Whh_p[((size_t)(tile * 8 + ks) * 64 + lane) * 8];
          acc[hcj][g] = __builtin_amdgcn_mfma_f32_16x16x32_bf16(a, b, acc[hcj][g], 0, 0, 0);
        }
      }
    }
    __syncthreads();  // all waves done reading h_sh

    // ---- nonlinearity + masked c/h update (C/D layout: row=mq*4+r, col=nl) ----
#pragma unroll
    for (int hcj = 0; hcj < 4; ++hcj) {
      const int hc = wave + 4 * hcj;
#pragma unroll
      for (int r = 0; r < 4; ++r) {
        const int m = mq * 4 + r;
        float gi = sigm(acc[hcj][0][r]);
        float gf = sigm(acc[hcj][1][r]);
        float gg = tanh_fast(acc[hcj][2][r]);
        float go = sigm(acc[hcj][3][r]);
        float cn = gf * c_reg[hcj][r] + gi * gg;
        if (t < len_sh[m]) {   // packed-seq mask: freeze after len
          c_reg[hcj][r] = cn;
          h_sh[m][hc * 16 + nl] = f2bf(go * tanh_fast(cn));
        }
      }
    }
    __syncthreads();  // h_sh updated

    if (MODE != 2) {
      unsigned short* dst = hseq_out + ((size_t)t * B_TOT + b0) * H_DIM;
      for (int i = tid; i < 512; i += 256) {
        int e = i * 8;
        int m = e >> 8, k = e & 255;
        *(short8*)&dst[e] = *(const short8*)&h_sh[m][k];
      }
    }
  }

  if (MODE == 2) {
#pragma unroll
    for (int hcj = 0; hcj < 4; ++hcj) {
      const int hc = wave + 4 * hcj;
#pragma unroll
      for (int r = 0; r < 4; ++r) {
        const int m = mq * 4 + r;
        c_out[(size_t)(b0 + m) * H_DIM + hc * 16 + nl] = c_reg[hcj][r];
      }
    }
  }
}

// ---------------------------------------------------------------------------
// Epilogue (all fp32, tiny)
// ---------------------------------------------------------------------------
__global__ void k_norm(const float* __restrict__ E, float* __restrict__ E1,
                       float* __restrict__ En) {
  int row  = blockIdx.x * 4 + (threadIdx.x >> 6);
  int lane = threadIdx.x & 63;
  const float* e = E + (size_t)row * H_DIM;
  float v[4]; float ss = 0.f;
#pragma unroll
  for (int j = 0; j < 4; ++j) { v[j] = e[lane + 64 * j]; ss += v[j] * v[j]; }
#pragma unroll
  for (int m = 32; m >= 1; m >>= 1) ss += __shfl_xor(ss, m, 64);
  float nrm  = sqrtf(ss);
  float inv1 = 1.f / fmaxf(nrm, 1e-12f);
  float inv2 = 1.f / fmaxf(nrm * inv1, 1e-8f);
#pragma unroll
  for (int j = 0; j < 4; ++j) {
    float e1 = v[j] * inv1;
    E1[(size_t)row * H_DIM + lane + 64 * j] = e1;
    En[(size_t)row * H_DIM + lane + 64 * j] = e1 * inv2;
  }
}

__global__ void k_cent(const float* __restrict__ E1, float* __restrict__ C,
                       float* __restrict__ CnT) {
  int n = blockIdx.x;
  int lane = threadIdx.x;  // 64
  float v[4]; float ss = 0.f;
#pragma unroll
  for (int j = 0; j < 4; ++j) {
    int col = lane + 64 * j;
    float s = 0.f;
    for (int m = 0; m < M_UTT; ++m) s += E1[((size_t)n * M_UTT + m) * H_DIM + col];
    v[j] = s / (float)M_UTT;
    ss += v[j] * v[j];
  }
#pragma unroll
  for (int m = 32; m >= 1; m >>= 1) ss += __shfl_xor(ss, m, 64);
  float inv = 1.f / fmaxf(sqrtf(ss), 1e-8f);
#pragma unroll
  for (int j = 0; j < 4; ++j) {
    int col = lane + 64 * j;
    C[(size_t)n * H_DIM + col]  = v[j];
    CnT[(size_t)col * N_SPK + n] = v[j] * inv;   // transposed for coalesced k_sim
  }
}

__global__ void k_cm(const float* __restrict__ E1, const float* __restrict__ C,
                     float* __restrict__ Cmn) {
  int b    = blockIdx.x * 4 + (threadIdx.x >> 6);
  int lane = threadIdx.x & 63;
  int spk  = b / M_UTT;
  float v[4]; float ss = 0.f;
#pragma unroll
  for (int j = 0; j < 4; ++j) {
    int col = lane + 64 * j;
    v[j] = ((float)M_UTT * C[(size_t)spk * H_DIM + col] + E1[(size_t)b * H_DIM + col])
           / (float)(M_UTT - 1);
    ss += v[j] * v[j];
  }
#pragma unroll
  for (int m = 32; m >= 1; m >>= 1) ss += __shfl_xor(ss, m, 64);
  float inv = 1.f / fmaxf(sqrtf(ss), 1e-8f);
#pragma unroll
  for (int j = 0; j < 4; ++j)
    Cmn[(size_t)b * H_DIM + lane + 64 * j] = v[j] * inv;
}

__global__ void k_sim(const float* __restrict__ En, const float* __restrict__ CnT,
                      const float* __restrict__ Cmn, const float* __restrict__ w_sim,
                      const float* __restrict__ b_sim, float* __restrict__ S) {
  int b = blockIdx.x;
  int n = threadIdx.x;  // 64
  int diag = b / M_UTT;
  float w = w_sim[0], bb = b_sim[0];
  float s = 0.f;
  for (int k = 0; k < H_DIM; ++k) {
    float en = En[(size_t)b * H_DIM + k];       // wave-uniform broadcast
    float c  = (n == diag) ? Cmn[(size_t)b * H_DIM + k] : CnT[(size_t)k * N_SPK + n];
    s += en * c;
  }
  S[(size_t)b * N_SPK + n] = s * w + bb;
}

// ---------------------------------------------------------------------------
// Workspace layout (bytes)
// ---------------------------------------------------------------------------
#define O_WIH0  0u            // 131072
#define O_WHH0  131072u       // 524288
#define O_WIH1  655360u
#define O_WHH1  1179648u
#define O_WIH2  1703936u
#define O_WHH2  2228224u
#define O_BIAS  2752512u      // 3*1024*4
#define O_HSEQ  2764800u      // 160*640*256*2 = 52428800 (in-place across layers)
#define O_E     55193600u     // 640*256*4
#define O_E1    55848960u
#define O_EN    56504320u
#define O_C     57159680u
#define O_CNT   57225216u
#define O_CMN   57290752u

extern "C" void kernel_launch(void* const* d_in, const int* in_sizes, int n_in,
                              void* d_out, int out_size, void* d_ws, size_t ws_size,
                              hipStream_t stream) {
  const float* seq   = (const float*)d_in[0];
  const int*   lens  = (const int*)d_in[1];
  const float* w_sim = (const float*)d_in[2];
  const float* b_sim = (const float*)d_in[3];
  const float* Wih[3] = {(const float*)d_in[4],  (const float*)d_in[8],  (const float*)d_in[12]};
  const float* Whh[3] = {(const float*)d_in[5],  (const float*)d_in[9],  (const float*)d_in[13]};
  const float* bih[3] = {(const float*)d_in[6],  (const float*)d_in[10], (const float*)d_in[14]};
  const float* bhh[3] = {(const float*)d_in[7],  (const float*)d_in[11], (const float*)d_in[15]};

  char* ws = (char*)d_ws;
  short* Wihp[3] = {(short*)(ws + O_WIH0), (short*)(ws + O_WIH1), (short*)(ws + O_WIH2)};
  short* Whhp[3] = {(short*)(ws + O_WHH0), (short*)(ws + O_WHH1), (short*)(ws + O_WHH2)};
  float* biasc   = (float*)(ws + O_BIAS);
  unsigned short* hseq = (unsigned short*)(ws + O_HSEQ);
  float* E   = (float*)(ws + O_E);
  float* E1  = (float*)(ws + O_E1);
  float* En  = (float*)(ws + O_EN);
  float* C   = (float*)(ws + O_C);
  float* CnT = (float*)(ws + O_CNT);
  float* Cmn = (float*)(ws + O_CMN);
  float* S   = (float*)d_out;

  // pack weights to bf16 MFMA B-fragment order; sum biases
  pack_w_kernel<<<32, 256, 0, stream>>>(Wih[0], Wihp[0], IN_F, 2);   // K pad 40->64
  pack_w_kernel<<<128, 256, 0, stream>>>(Whh[0], Whhp[0], H_DIM, 8);
  pack_w_kernel<<<128, 256, 0, stream>>>(Wih[1], Wihp[1], H_DIM, 8);
  pack_w_kernel<<<128, 256, 0, stream>>>(Whh[1], Whhp[1], H_DIM, 8);
  pack_w_kernel<<<128, 256, 0, stream>>>(Wih[2], Wihp[2], H_DIM, 8);
  pack_w_kernel<<<128, 256, 0, stream>>>(Whh[2], Whhp[2], H_DIM, 8);
  for (int l = 0; l < 3; ++l)
    bias_sum_kernel<<<4, 256, 0, stream>>>(bih[l], bhh[l], biasc + l * G4);

  // 3 LSTM layers (hseq reused in-place)
  lstm_kernel<64, 0><<<B_TOT / 16, 256, 0, stream>>>(seq, nullptr, hseq,
      Wihp[0], Whhp[0], biasc, lens, nullptr);
  lstm_kernel<256, 1><<<B_TOT / 16, 256, 0, stream>>>(nullptr, hseq, hseq,
      Wihp[1], Whhp[1], biasc + G4, lens, nullptr);
  lstm_kernel<256, 2><<<B_TOT / 16, 256, 0, stream>>>(nullptr, hseq, nullptr,
      Wihp[2], Whhp[2], biasc + 2 * G4, lens, E);

  // similarity epilogue
  k_norm<<<160, 256, 0, stream>>>(E, E1, En);
  k_cent<<<N_SPK, 64, 0, stream>>>(E1, C, CnT);
  k_cm<<<160, 256, 0, stream>>>(E1, C, Cmn);
  k_sim<<<B_TOT, 64, 0, stream>>>(En, CnT, Cmn, w_sim, b_sim, S);
}

// Round 3
// 4224.217 us; speedup vs baseline: 2.4224x; 2.4224x over previous
//
#include <hip/hip_runtime.h>
#include <cstdint>
#include <cstddef>

typedef __attribute__((ext_vector_type(8))) short short8;
typedef __attribute__((ext_vector_type(4))) float f32x4;
typedef __attribute__((ext_vector_type(4))) unsigned short us4;

#define N_SPK 64
#define M_UTT 10
#define T_SEQ 160
#define IN_F  40
#define H_DIM 256
#define B_TOT 640
#define G4    1024

__device__ __forceinline__ unsigned short f2bf(float f) {
  unsigned int u = __float_as_uint(f);
  u += 0x7FFFu + ((u >> 16) & 1u);   // round-to-nearest-even
  return (unsigned short)(u >> 16);
}
__device__ __forceinline__ float b2f(unsigned short u) {
  return __uint_as_float(((unsigned int)u) << 16);
}
__device__ __forceinline__ float sigm(float x) {
  x = fminf(fmaxf(x, -30.f), 30.f);
  return 1.f / (1.f + __expf(-x));
}
__device__ __forceinline__ float tanh_fast(float x) {
  x = fminf(fmaxf(x, -15.f), 15.f);
  float e = __expf(2.f * x);
  return (e - 1.f) / (e + 1.f);
}

// ---------------------------------------------------------------------------
// Weight pack: B-fragment order for mfma_f32_16x16x32_bf16 (verified R1).
// out[((tile*Ktiles + ks)*64 + lane)*8 + j] = W[tile*16+(lane&15)][ks*32+(lane>>4)*8+j]
// ---------------------------------------------------------------------------
__global__ void pack_w_kernel(const float* __restrict__ W, short* __restrict__ out,
                              int Kin, int Ktiles) {
  int idx = blockIdx.x * 256 + threadIdx.x;
  int total = 64 * Ktiles * 64;
  if (idx >= total) return;
  int lane = idx & 63;
  int rest = idx >> 6;
  int ks   = rest % Ktiles;
  int tile = rest / Ktiles;
  int n  = tile * 16 + (lane & 15);
  int k0 = ks * 32 + (lane >> 4) * 8;
  short8 v;
#pragma unroll
  for (int j = 0; j < 8; ++j) {
    int k = k0 + j;
    float f = (k < Kin) ? W[(size_t)n * Kin + k] : 0.f;
    v[j] = (short)f2bf(f);
  }
  *(short8*)&out[(size_t)idx * 8] = v;
}

__global__ void bias_sum_kernel(const float* __restrict__ a, const float* __restrict__ b,
                                float* __restrict__ o) {
  int i = blockIdx.x * 256 + threadIdx.x;
  if (i < G4) o[i] = a[i] + b[i];
}

// ---------------------------------------------------------------------------
// Phase A: G_chunk[slot][btile][tile][lane][4] (bf16, C-layout) = X@Wih^T + bias
// One block = 4 time steps x one btile (16 samples). Grid = 40 * (steps/4).
// Wave w owns tiles {g*16 + w + 4q}. L0=1: read fp32 seq directly (K pad 40->64).
// ---------------------------------------------------------------------------
template<int KT, int L0>
__global__ __launch_bounds__(256, 1)
void gate_gemm(const float* __restrict__ seq, const unsigned short* __restrict__ Xf,
               const short* __restrict__ Wp, const float* __restrict__ bias,
               unsigned short* __restrict__ G, int chunk_t0) {
  const int btile = blockIdx.x % 40;
  const int slot0 = (blockIdx.x / 40) * 4;
  const int t0 = chunk_t0 + slot0;
  const int tid = threadIdx.x, lane = tid & 63, wave = tid >> 6;
  const int nl = lane & 15, mq = lane >> 4;

  f32x4 acc[4][16];
#pragma unroll
  for (int q = 0; q < 4; ++q)
#pragma unroll
    for (int g = 0; g < 4; ++g) {
      int tile = g * 16 + wave + 4 * q;
      float bv = bias[tile * 16 + nl];
#pragma unroll
      for (int mm = 0; mm < 4; ++mm) acc[mm][q * 4 + g] = (f32x4){bv, bv, bv, bv};
    }

  for (int kt = 0; kt < KT; ++kt) {
    short8 a[4];
    if (L0) {
      const int m = btile * 16 + nl;
      const int k0 = kt * 32 + mq * 8;
#pragma unroll
      for (int mm = 0; mm < 4; ++mm) {
#pragma unroll
        for (int j = 0; j < 8; ++j) {
          int k = k0 + j;
          float f = (k < IN_F) ? seq[((size_t)m * T_SEQ + (t0 + mm)) * IN_F + k] : 0.f;
          a[mm][j] = (short)f2bf(f);
        }
      }
    } else {
#pragma unroll
      for (int mm = 0; mm < 4; ++mm)
        a[mm] = *(const short8*)&Xf[(((size_t)(t0 + mm) * 40 + btile) * KT + kt) * 512 + lane * 8];
    }
#pragma unroll
    for (int q = 0; q < 4; ++q)
#pragma unroll
      for (int g = 0; g < 4; ++g) {
        int tile = g * 16 + wave + 4 * q;
        short8 b = *(const short8*)&Wp[(((size_t)tile * KT + kt) * 64 + lane) * 8];
#pragma unroll
        for (int mm = 0; mm < 4; ++mm)
          acc[mm][q * 4 + g] = __builtin_amdgcn_mfma_f32_16x16x32_bf16(a[mm], b, acc[mm][q * 4 + g], 0, 0, 0);
      }
  }
#pragma unroll
  for (int mm = 0; mm < 4; ++mm)
#pragma unroll
    for (int q = 0; q < 4; ++q)
#pragma unroll
      for (int g = 0; g < 4; ++g) {
        int tile = g * 16 + wave + 4 * q;
        us4 o;
#pragma unroll
        for (int r = 0; r < 4; ++r) o[r] = f2bf(acc[mm][q * 4 + g][r]);
        *(us4*)&G[(((size_t)(slot0 + mm) * 40 + btile) * 64 + tile) * 256 + lane * 4] = o;
      }
}

// ---------------------------------------------------------------------------
// Phase B: recurrence, Whh CU-resident (384 VGPR/lane + 128 KB LDS).
// One block = 16 samples (btile). State (c fp32, h bf16) round-trips through
// global buffers at chunk boundaries (zeroed per layer by hipMemsetAsync).
// WRITE_H: also store h_t to hseq (A-frag layout) for next layer's phase A.
// ---------------------------------------------------------------------------
template<int WRITE_H>
__global__ __launch_bounds__(256, 1)
void lstm_rec(const short* __restrict__ Whh_p, const unsigned short* __restrict__ G,
              const int* __restrict__ lens, unsigned short* __restrict__ hseq,
              unsigned short* __restrict__ h_state, float* __restrict__ c_state,
              int t_start, int t_end) {
  const int btile = blockIdx.x;
  const int tid = threadIdx.x, lane = tid & 63, wave = tid >> 6;
  const int mq = lane >> 4, nl = lane & 15;

  __shared__ short wlds[128 * 512];          // kt 6..7 of all 64 tiles (128 KB)
  __shared__ unsigned short h_sh[16][264];   // rows=samples, 16B-aligned stride

  // LDS-resident weights: kt 6..7
  for (int i = tid; i < 128 * 64; i += 256) {
    int tl = i >> 6, ln = i & 63;
    int tile = tl >> 1, kt = 6 + (tl & 1);
    *(short8*)&wlds[(size_t)i * 8] =
        *(const short8*)&Whh_p[(((size_t)tile * 8 + kt) * 64 + ln) * 8];
  }
  // Register-resident weights: kt 0..5 of this wave's 16 tiles
  short8 wreg[96];
#pragma unroll
  for (int q = 0; q < 4; ++q)
#pragma unroll
    for (int g = 0; g < 4; ++g)
#pragma unroll
      for (int kt = 0; kt < 6; ++kt) {
        int tile = g * 16 + wave + 4 * q;
        wreg[(q * 4 + g) * 6 + kt] =
            *(const short8*)&Whh_p[(((size_t)tile * 8 + kt) * 64 + lane) * 8];
      }
  // load h state (16 samples x 256, bf16)
  for (int i = tid; i < 512; i += 256) {
    int m = i >> 5, k8 = i & 31;
    *(short8*)&h_sh[m][k8 * 8] = *(const short8*)&h_state[(size_t)btile * 4096 + (size_t)i * 8];
  }
  // load c state
  float c_reg[16];
#pragma unroll
  for (int q = 0; q < 4; ++q)
#pragma unroll
    for (int r = 0; r < 4; ++r)
      c_reg[q * 4 + r] = c_state[(size_t)btile * 4096 + (mq * 4 + r) * 256 + (wave + 4 * q) * 16 + nl];
  int lenr[4];
#pragma unroll
  for (int r = 0; r < 4; ++r) lenr[r] = lens[btile * 16 + mq * 4 + r];
  __syncthreads();

  for (int t = t_start; t < t_end; ++t) {
    const unsigned short* gb = G + ((size_t)(t - t_start) * 40 + btile) * 16384 + lane * 4;
    us4 gv[16];
#pragma unroll
    for (int q = 0; q < 4; ++q)
#pragma unroll
      for (int g = 0; g < 4; ++g) {
        int tile = g * 16 + wave + 4 * q;
        gv[q * 4 + g] = *(const us4*)&gb[(size_t)tile * 256];
      }

    unsigned short hnew[16];
#pragma unroll
    for (int half = 0; half < 2; ++half) {
      f32x4 acc[8];
#pragma unroll
      for (int j = 0; j < 8; ++j) acc[j] = (f32x4){0.f, 0.f, 0.f, 0.f};
#pragma unroll
      for (int kt = 0; kt < 8; ++kt) {
        short8 a = *(const short8*)&h_sh[nl][kt * 32 + mq * 8];
#pragma unroll
        for (int hc2 = 0; hc2 < 2; ++hc2)
#pragma unroll
          for (int g = 0; g < 4; ++g) {
            const int q = half * 2 + hc2;
            short8 b;
            if (kt < 6) {
              b = wreg[(q * 4 + g) * 6 + kt];
            } else {
              const int tile = g * 16 + wave + 4 * q;
              b = *(const short8*)&wlds[((size_t)tile * 2 + (kt - 6)) * 512 + lane * 8];
            }
            acc[hc2 * 4 + g] =
                __builtin_amdgcn_mfma_f32_16x16x32_bf16(a, b, acc[hc2 * 4 + g], 0, 0, 0);
          }
      }
#pragma unroll
      for (int hc2 = 0; hc2 < 2; ++hc2) {
        const int q = half * 2 + hc2;
        const int hc = wave + 4 * q;
#pragma unroll
        for (int r = 0; r < 4; ++r) {
          float xi = acc[hc2 * 4 + 0][r] + b2f(gv[q * 4 + 0][r]);
          float xf = acc[hc2 * 4 + 1][r] + b2f(gv[q * 4 + 1][r]);
          float xg = acc[hc2 * 4 + 2][r] + b2f(gv[q * 4 + 2][r]);
          float xo = acc[hc2 * 4 + 3][r] + b2f(gv[q * 4 + 3][r]);
          float cn = sigm(xf) * c_reg[q * 4 + r] + sigm(xi) * tanh_fast(xg);
          float hn = sigm(xo) * tanh_fast(cn);
          bool upd = (t < lenr[r]);
          if (upd) c_reg[q * 4 + r] = cn;
          hnew[q * 4 + r] = upd ? f2bf(hn) : h_sh[mq * 4 + r][hc * 16 + nl];
        }
      }
    }
    __syncthreads();   // all waves done reading h_sh
#pragma unroll
    for (int q = 0; q < 4; ++q) {
      const int hc = wave + 4 * q;
#pragma unroll
      for (int r = 0; r < 4; ++r)
        h_sh[mq * 4 + r][hc * 16 + nl] = hnew[q * 4 + r];
    }
    __syncthreads();   // h_sh updated
    if (WRITE_H) {
#pragma unroll
      for (int kk = 0; kk < 2; ++kk) {
        int kt = wave * 2 + kk;
        short8 v = *(const short8*)&h_sh[nl][kt * 32 + mq * 8];
        *(short8*)&hseq[(((size_t)t * 40 + btile) * 8 + kt) * 512 + lane * 8] = v;
      }
    }
  }

  // store state for next chunk (h_sh consistent after final sync)
  for (int i = tid; i < 512; i += 256) {
    int m = i >> 5, k8 = i & 31;
    *(short8*)&h_state[(size_t)btile * 4096 + (size_t)i * 8] = *(const short8*)&h_sh[m][k8 * 8];
  }
#pragma unroll
  for (int q = 0; q < 4; ++q)
#pragma unroll
    for (int r = 0; r < 4; ++r)
      c_state[(size_t)btile * 4096 + (mq * 4 + r) * 256 + (wave + 4 * q) * 16 + nl] = c_reg[q * 4 + r];
}

// ---------------------------------------------------------------------------
// Epilogue (verified R1). E aliases c_state (c frozen at last valid step).
// ---------------------------------------------------------------------------
__global__ void k_norm(const float* __restrict__ E, float* __restrict__ E1,
                       float* __restrict__ En) {
  int row  = blockIdx.x * 4 + (threadIdx.x >> 6);
  int lane = threadIdx.x & 63;
  const float* e = E + (size_t)row * H_DIM;
  float v[4]; float ss = 0.f;
#pragma unroll
  for (int j = 0; j < 4; ++j) { v[j] = e[lane + 64 * j]; ss += v[j] * v[j]; }
#pragma unroll
  for (int m = 32; m >= 1; m >>= 1) ss += __shfl_xor(ss, m, 64);
  float nrm  = sqrtf(ss);
  float inv1 = 1.f / fmaxf(nrm, 1e-12f);
  float inv2 = 1.f / fmaxf(nrm * inv1, 1e-8f);
#pragma unroll
  for (int j = 0; j < 4; ++j) {
    float e1 = v[j] * inv1;
    E1[(size_t)row * H_DIM + lane + 64 * j] = e1;
    En[(size_t)row * H_DIM + lane + 64 * j] = e1 * inv2;
  }
}

__global__ void k_cent(const float* __restrict__ E1, float* __restrict__ C,
                       float* __restrict__ CnT) {
  int n = blockIdx.x;
  int lane = threadIdx.x;  // 64
  float v[4]; float ss = 0.f;
#pragma unroll
  for (int j = 0; j < 4; ++j) {
    int col = lane + 64 * j;
    float s = 0.f;
    for (int m = 0; m < M_UTT; ++m) s += E1[((size_t)n * M_UTT + m) * H_DIM + col];
    v[j] = s / (float)M_UTT;
    ss += v[j] * v[j];
  }
#pragma unroll
  for (int m = 32; m >= 1; m >>= 1) ss += __shfl_xor(ss, m, 64);
  float inv = 1.f / fmaxf(sqrtf(ss), 1e-8f);
#pragma unroll
  for (int j = 0; j < 4; ++j) {
    int col = lane + 64 * j;
    C[(size_t)n * H_DIM + col]  = v[j];
    CnT[(size_t)col * N_SPK + n] = v[j] * inv;
  }
}

__global__ void k_cm(const float* __restrict__ E1, const float* __restrict__ C,
                     float* __restrict__ Cmn) {
  int b    = blockIdx.x * 4 + (threadIdx.x >> 6);
  int lane = threadIdx.x & 63;
  int spk  = b / M_UTT;
  float v[4]; float ss = 0.f;
#pragma unroll
  for (int j = 0; j < 4; ++j) {
    int col = lane + 64 * j;
    v[j] = ((float)M_UTT * C[(size_t)spk * H_DIM + col] + E1[(size_t)b * H_DIM + col])
           / (float)(M_UTT - 1);
    ss += v[j] * v[j];
  }
#pragma unroll
  for (int m = 32; m >= 1; m >>= 1) ss += __shfl_xor(ss, m, 64);
  float inv = 1.f / fmaxf(sqrtf(ss), 1e-8f);
#pragma unroll
  for (int j = 0; j < 4; ++j)
    Cmn[(size_t)b * H_DIM + lane + 64 * j] = v[j] * inv;
}

__global__ void k_sim(const float* __restrict__ En, const float* __restrict__ CnT,
                      const float* __restrict__ Cmn, const float* __restrict__ w_sim,
                      const float* __restrict__ b_sim, float* __restrict__ S) {
  int b = blockIdx.x;
  int n = threadIdx.x;  // 64
  int diag = b / M_UTT;
  float w = w_sim[0], bb = b_sim[0];
  float s = 0.f;
  for (int k = 0; k < H_DIM; ++k) {
    float en = En[(size_t)b * H_DIM + k];
    float c  = (n == diag) ? Cmn[(size_t)b * H_DIM + k] : CnT[(size_t)k * N_SPK + n];
    s += en * c;
  }
  S[(size_t)b * N_SPK + n] = s * w + bb;
}

// ---------------------------------------------------------------------------
// Workspace layout (bytes). Fixed part = 56,176,640; G chunk (TC*1,310,720)
// sized at runtime from ws_size. Epilogue buffers overlay the G region.
// ---------------------------------------------------------------------------
#define O_WHH   0ull            // 3 x 524288
#define O_WIH0  1572864ull      // 131072
#define O_WIH1  1703936ull      // 524288
#define O_WIH2  2228224ull      // 524288
#define O_BIAS  2752512ull      // 12288
#define O_CST   2764800ull      // 655360  (fp32 c state; == E at the end)
#define O_HST   3420160ull      // 327680  (bf16 h state)
#define O_HSEQ  3747840ull      // 52428800
#define O_G     56176640ull     // TC * 1310720

extern "C" void kernel_launch(void* const* d_in, const int* in_sizes, int n_in,
                              void* d_out, int out_size, void* d_ws, size_t ws_size,
                              hipStream_t stream) {
  const float* seq   = (const float*)d_in[0];
  const int*   lens  = (const int*)d_in[1];
  const float* w_sim = (const float*)d_in[2];
  const float* b_sim = (const float*)d_in[3];
  const float* Wih[3] = {(const float*)d_in[4],  (const float*)d_in[8],  (const float*)d_in[12]};
  const float* Whh[3] = {(const float*)d_in[5],  (const float*)d_in[9],  (const float*)d_in[13]};
  const float* bih[3] = {(const float*)d_in[6],  (const float*)d_in[10], (const float*)d_in[14]};
  const float* bhh[3] = {(const float*)d_in[7],  (const float*)d_in[11], (const float*)d_in[15]};

  char* ws = (char*)d_ws;
  short* Whhp[3] = {(short*)(ws + O_WHH), (short*)(ws + O_WHH + 524288),
                    (short*)(ws + O_WHH + 1048576)};
  short* Wihp[3] = {(short*)(ws + O_WIH0), (short*)(ws + O_WIH1), (short*)(ws + O_WIH2)};
  float* biasc = (float*)(ws + O_BIAS);
  float* c_state = (float*)(ws + O_CST);
  unsigned short* h_state = (unsigned short*)(ws + O_HST);
  unsigned short* hseq = (unsigned short*)(ws + O_HSEQ);
  unsigned short* G    = (unsigned short*)(ws + O_G);
  // epilogue overlays the G region (G is dead by then); needs 2 MB <= TC*1.31 MB
  float* E1  = (float*)(ws + O_G);
  float* En  = (float*)(ws + O_G + 655360);
  float* C   = (float*)(ws + O_G + 1310720);
  float* CnT = (float*)(ws + O_G + 1376256);
  float* Cmn = (float*)(ws + O_G + 1441792);
  float* S   = (float*)d_out;

  // runtime time-chunk size from available workspace (deterministic per call)
  const size_t base = O_G, per4 = 4ull * 40 * 64 * 256 * 2;  // 5,242,880 B
  int units = (ws_size > base) ? (int)((ws_size - base) / per4) : 0;
  int TC = units * 4;
  if (TC > T_SEQ) TC = T_SEQ;
  if (TC < 4) TC = 4;   // last resort (ws barely above base)

  // ---- packs ----
  pack_w_kernel<<<32, 256, 0, stream>>>(Wih[0], Wihp[0], IN_F, 2);
  pack_w_kernel<<<128, 256, 0, stream>>>(Whh[0], Whhp[0], H_DIM, 8);
  pack_w_kernel<<<128, 256, 0, stream>>>(Wih[1], Wihp[1], H_DIM, 8);
  pack_w_kernel<<<128, 256, 0, stream>>>(Whh[1], Whhp[1], H_DIM, 8);
  pack_w_kernel<<<128, 256, 0, stream>>>(Wih[2], Wihp[2], H_DIM, 8);
  pack_w_kernel<<<128, 256, 0, stream>>>(Whh[2], Whhp[2], H_DIM, 8);
  for (int l = 0; l < 3; ++l)
    bias_sum_kernel<<<4, 256, 0, stream>>>(bih[l], bhh[l], biasc + l * G4);

  // ---- 3 layers, chunked over time ----
  for (int l = 0; l < 3; ++l) {
    hipMemsetAsync(c_state, 0, 655360, stream);
    hipMemsetAsync(h_state, 0, 327680, stream);
    for (int t0 = 0; t0 < T_SEQ; t0 += TC) {
      int steps = T_SEQ - t0; if (steps > TC) steps = TC;
      int ggrid = 40 * (steps / 4);
      if (l == 0)
        gate_gemm<2, 1><<<ggrid, 256, 0, stream>>>(seq, nullptr, Wihp[0], biasc, G, t0);
      else
        gate_gemm<8, 0><<<ggrid, 256, 0, stream>>>(nullptr, hseq, Wihp[l], biasc + l * G4, G, t0);
      if (l < 2)
        lstm_rec<1><<<40, 256, 0, stream>>>(Whhp[l], G, lens, hseq, h_state, c_state, t0, t0 + steps);
      else
        lstm_rec<0><<<40, 256, 0, stream>>>(Whhp[l], G, lens, nullptr, h_state, c_state, t0, t0 + steps);
    }
  }

  // ---- similarity epilogue (E = c_state) ----
  k_norm<<<160, 256, 0, stream>>>(c_state, E1, En);
  k_cent<<<N_SPK, 64, 0, stream>>>(E1, C, CnT);
  k_cm<<<160, 256, 0, stream>>>(E1, C, Cmn);
  k_sim<<<B_TOT, 64, 0, stream>>>(En, CnT, Cmn, w_sim, b_sim, S);
}

// Round 4
// 3026.135 us; speedup vs baseline: 3.3815x; 1.3959x over previous
//
#include <hip/hip_runtime.h>
#include <cstdint>
#include <cstddef>

typedef __attribute__((ext_vector_type(8))) short short8;
typedef __attribute__((ext_vector_type(4))) float f32x4;
typedef __attribute__((ext_vector_type(4))) unsigned short us4;

#define N_SPK 64
#define M_UTT 10
#define T_SEQ 160
#define IN_F  40
#define H_DIM 256
#define B_TOT 640
#define G4    1024

__device__ __forceinline__ unsigned short f2bf(float f) {
  unsigned int u = __float_as_uint(f);
  u += 0x7FFFu + ((u >> 16) & 1u);   // round-to-nearest-even
  return (unsigned short)(u >> 16);
}
__device__ __forceinline__ float b2f(unsigned short u) {
  return __uint_as_float(((unsigned int)u) << 16);
}
// clamp-free: exp underflow/overflow saturates exactly to {0,1}/{-1,1}
__device__ __forceinline__ float sigm(float x) {
  return 1.f / (1.f + __expf(-x));
}
__device__ __forceinline__ float tanh_fast(float x) {
  return 1.f - 2.f / (1.f + __expf(2.f * x));
}

// ---------------------------------------------------------------------------
// Weight pack: B-fragment order for mfma_f32_16x16x32_bf16 (verified R1/R3).
// out[((tile*Ktiles + ks)*64 + lane)*8 + j] = W[tile*16+(lane&15)][ks*32+(lane>>4)*8+j]
// ---------------------------------------------------------------------------
__global__ void pack_w_kernel(const float* __restrict__ W, short* __restrict__ out,
                              int Kin, int Ktiles) {
  int idx = blockIdx.x * 256 + threadIdx.x;
  int total = 64 * Ktiles * 64;
  if (idx >= total) return;
  int lane = idx & 63;
  int rest = idx >> 6;
  int ks   = rest % Ktiles;
  int tile = rest / Ktiles;
  int n  = tile * 16 + (lane & 15);
  int k0 = ks * 32 + (lane >> 4) * 8;
  short8 v;
#pragma unroll
  for (int j = 0; j < 8; ++j) {
    int k = k0 + j;
    float f = (k < Kin) ? W[(size_t)n * Kin + k] : 0.f;
    v[j] = (short)f2bf(f);
  }
  *(short8*)&out[(size_t)idx * 8] = v;
}

__global__ void bias_sum_kernel(const float* __restrict__ a, const float* __restrict__ b,
                                float* __restrict__ o) {
  int i = blockIdx.x * 256 + threadIdx.x;
  if (i < G4) o[i] = a[i] + b[i];
}

// ---------------------------------------------------------------------------
// Phase A: G_chunk[slot][btile][tile][lane][4] (bf16, C-layout) = X@Wih^T + bias
// One block = 4 time steps x one btile (16 samples). Grid = 40 * (steps/4).
// ---------------------------------------------------------------------------
template<int KT, int L0>
__global__ __launch_bounds__(256, 1)
void gate_gemm(const float* __restrict__ seq, const unsigned short* __restrict__ Xf,
               const short* __restrict__ Wp, const float* __restrict__ bias,
               unsigned short* __restrict__ G, int chunk_t0) {
  const int btile = blockIdx.x % 40;
  const int slot0 = (blockIdx.x / 40) * 4;
  const int t0 = chunk_t0 + slot0;
  const int tid = threadIdx.x, lane = tid & 63, wave = tid >> 6;
  const int nl = lane & 15, mq = lane >> 4;

  f32x4 acc[4][16];
#pragma unroll
  for (int q = 0; q < 4; ++q)
#pragma unroll
    for (int g = 0; g < 4; ++g) {
      int tile = g * 16 + wave + 4 * q;
      float bv = bias[tile * 16 + nl];
#pragma unroll
      for (int mm = 0; mm < 4; ++mm) acc[mm][q * 4 + g] = (f32x4){bv, bv, bv, bv};
    }

  for (int kt = 0; kt < KT; ++kt) {
    short8 a[4];
    if (L0) {
      const int m = btile * 16 + nl;
      const int k0 = kt * 32 + mq * 8;
#pragma unroll
      for (int mm = 0; mm < 4; ++mm) {
#pragma unroll
        for (int j = 0; j < 8; ++j) {
          int k = k0 + j;
          float f = (k < IN_F) ? seq[((size_t)m * T_SEQ + (t0 + mm)) * IN_F + k] : 0.f;
          a[mm][j] = (short)f2bf(f);
        }
      }
    } else {
#pragma unroll
      for (int mm = 0; mm < 4; ++mm)
        a[mm] = *(const short8*)&Xf[(((size_t)(t0 + mm) * 40 + btile) * KT + kt) * 512 + lane * 8];
    }
#pragma unroll
    for (int q = 0; q < 4; ++q)
#pragma unroll
      for (int g = 0; g < 4; ++g) {
        int tile = g * 16 + wave + 4 * q;
        short8 b = *(const short8*)&Wp[(((size_t)tile * KT + kt) * 64 + lane) * 8];
#pragma unroll
        for (int mm = 0; mm < 4; ++mm)
          acc[mm][q * 4 + g] = __builtin_amdgcn_mfma_f32_16x16x32_bf16(a[mm], b, acc[mm][q * 4 + g], 0, 0, 0);
      }
  }
#pragma unroll
  for (int mm = 0; mm < 4; ++mm)
#pragma unroll
    for (int q = 0; q < 4; ++q)
#pragma unroll
      for (int g = 0; g < 4; ++g) {
        int tile = g * 16 + wave + 4 * q;
        us4 o;
#pragma unroll
        for (int r = 0; r < 4; ++r) o[r] = f2bf(acc[mm][q * 4 + g][r]);
        *(us4*)&G[(((size_t)(slot0 + mm) * 40 + btile) * 64 + tile) * 256 + lane * 4] = o;
      }
}

// ---------------------------------------------------------------------------
// Phase B: recurrence, Whh CU-resident without scratch spill (R3 fix).
// 512 threads = 8 waves. Wave w owns hc in {w, w+8} x 4 gates = 8 tiles:
//   regs: kt 0..5 -> 48 short8 = 192 VGPR   (fits the 256-VGPR arch cap)
//   LDS : kt 6..7 of all 64 tiles (128 KB)
// Per step/wave: 64 MFMA, 8 a-frag ds_read_b128, 16 B-frag ds_read_b128.
// Previous h kept in regs (hreg) to avoid LDS readback for the mask path.
// ---------------------------------------------------------------------------
template<int WRITE_H>
__global__ __launch_bounds__(512, 1)
void lstm_rec(const short* __restrict__ Whh_p, const unsigned short* __restrict__ G,
              const int* __restrict__ lens, unsigned short* __restrict__ hseq,
              unsigned short* __restrict__ h_state, float* __restrict__ c_state,
              int t_start, int t_end) {
  const int btile = blockIdx.x;
  const int tid = threadIdx.x, lane = tid & 63, wave = tid >> 6;  // wave 0..7
  const int mq = lane >> 4, nl = lane & 15;

  __shared__ short wlds[2][64][512];         // [kt-6][tile][lane*8]  = 128 KB
  __shared__ unsigned short h_sh[16][264];   // 16 samples x 256 (+pad)

  // LDS-resident weights: kt 6..7, all 64 tiles
  for (int i = tid; i < 128 * 64; i += 512) {
    int tl = i >> 6, ln = i & 63;
    int kt = tl >> 6, tile = tl & 63;
    *(short8*)&wlds[kt][tile][ln * 8] =
        *(const short8*)&Whh_p[(((size_t)tile * 8 + 6 + kt) * 64 + ln) * 8];
  }
  // Register-resident weights: kt 0..5 of this wave's 8 tiles
  short8 wreg[8][6];
#pragma unroll
  for (int hcj = 0; hcj < 2; ++hcj)
#pragma unroll
    for (int g = 0; g < 4; ++g) {
      const int tile = g * 16 + wave + 8 * hcj;
#pragma unroll
      for (int kt = 0; kt < 6; ++kt)
        wreg[hcj * 4 + g][kt] =
            *(const short8*)&Whh_p[(((size_t)tile * 8 + kt) * 64 + lane) * 8];
    }
  // h state -> LDS
  for (int i = tid; i < 512; i += 512)
    *(short8*)&h_sh[i >> 5][(i & 31) * 8] =
        *(const short8*)&h_state[(size_t)btile * 4096 + (size_t)i * 8];
  // c state -> regs
  float c_reg[8];
#pragma unroll
  for (int hcj = 0; hcj < 2; ++hcj)
#pragma unroll
    for (int r = 0; r < 4; ++r)
      c_reg[hcj * 4 + r] =
          c_state[(size_t)btile * 4096 + (size_t)(mq * 4 + r) * 256 + (wave + 8 * hcj) * 16 + nl];
  int lenr[4];
#pragma unroll
  for (int r = 0; r < 4; ++r) lenr[r] = lens[btile * 16 + mq * 4 + r];
  __syncthreads();
  // previous-h mirror in regs (exactly the entries this wave owns/writes)
  unsigned short hreg[8];
#pragma unroll
  for (int hcj = 0; hcj < 2; ++hcj)
#pragma unroll
    for (int r = 0; r < 4; ++r)
      hreg[hcj * 4 + r] = h_sh[mq * 4 + r][(wave + 8 * hcj) * 16 + nl];

  for (int t = t_start; t < t_end; ++t) {
    f32x4 acc[8];
#pragma unroll
    for (int j = 0; j < 8; ++j) acc[j] = (f32x4){0.f, 0.f, 0.f, 0.f};
#pragma unroll
    for (int kt = 0; kt < 8; ++kt) {
      short8 a = *(const short8*)&h_sh[nl][kt * 32 + mq * 8];
#pragma unroll
      for (int hcj = 0; hcj < 2; ++hcj)
#pragma unroll
        for (int g = 0; g < 4; ++g) {
          short8 b;
          if (kt < 6) {
            b = wreg[hcj * 4 + g][kt];
          } else {
            const int tile = g * 16 + wave + 8 * hcj;
            b = *(const short8*)&wlds[kt - 6][tile][lane * 8];
          }
          acc[hcj * 4 + g] =
              __builtin_amdgcn_mfma_f32_16x16x32_bf16(a, b, acc[hcj * 4 + g], 0, 0, 0);
        }
    }
    // gate pre-activations from G (L2/LLC-hot, written by gate_gemm)
    const unsigned short* gb = G + ((size_t)(t - t_start) * 40 + btile) * 16384 + lane * 4;
#pragma unroll
    for (int hcj = 0; hcj < 2; ++hcj) {
      const int hc = wave + 8 * hcj;
      us4 g0 = *(const us4*)&gb[(size_t)(0 * 16 + hc) * 256];
      us4 g1 = *(const us4*)&gb[(size_t)(1 * 16 + hc) * 256];
      us4 g2 = *(const us4*)&gb[(size_t)(2 * 16 + hc) * 256];
      us4 g3 = *(const us4*)&gb[(size_t)(3 * 16 + hc) * 256];
#pragma unroll
      for (int r = 0; r < 4; ++r) {
        float xi = acc[hcj * 4 + 0][r] + b2f(g0[r]);
        float xf = acc[hcj * 4 + 1][r] + b2f(g1[r]);
        float xg = acc[hcj * 4 + 2][r] + b2f(g2[r]);
        float xo = acc[hcj * 4 + 3][r] + b2f(g3[r]);
        float cn = sigm(xf) * c_reg[hcj * 4 + r] + sigm(xi) * tanh_fast(xg);
        float hn = sigm(xo) * tanh_fast(cn);
        bool upd = (t < lenr[r]);
        if (upd) {
          c_reg[hcj * 4 + r] = cn;
          hreg[hcj * 4 + r] = f2bf(hn);
        }
      }
    }
    __syncthreads();   // all waves done reading h_sh
#pragma unroll
    for (int hcj = 0; hcj < 2; ++hcj) {
      const int hc = wave + 8 * hcj;
#pragma unroll
      for (int r = 0; r < 4; ++r)
        h_sh[mq * 4 + r][hc * 16 + nl] = hreg[hcj * 4 + r];
    }
    __syncthreads();   // h_sh updated
    if (WRITE_H) {
      // store h_t in A-fragment layout (kt = wave) for next layer's gate_gemm
      short8 v = *(const short8*)&h_sh[nl][wave * 32 + mq * 8];
      *(short8*)&hseq[(((size_t)t * 40 + btile) * 8 + wave) * 512 + lane * 8] = v;
    }
  }

  // store state for next chunk
  for (int i = tid; i < 512; i += 512)
    *(short8*)&h_state[(size_t)btile * 4096 + (size_t)i * 8] =
        *(const short8*)&h_sh[i >> 5][(i & 31) * 8];
#pragma unroll
  for (int hcj = 0; hcj < 2; ++hcj)
#pragma unroll
    for (int r = 0; r < 4; ++r)
      c_state[(size_t)btile * 4096 + (size_t)(mq * 4 + r) * 256 + (wave + 8 * hcj) * 16 + nl] =
          c_reg[hcj * 4 + r];
}

// ---------------------------------------------------------------------------
// Epilogue (verified R1/R3). E aliases c_state.
// ---------------------------------------------------------------------------
__global__ void k_norm(const float* __restrict__ E, float* __restrict__ E1,
                       float* __restrict__ En) {
  int row  = blockIdx.x * 4 + (threadIdx.x >> 6);
  int lane = threadIdx.x & 63;
  const float* e = E + (size_t)row * H_DIM;
  float v[4]; float ss = 0.f;
#pragma unroll
  for (int j = 0; j < 4; ++j) { v[j] = e[lane + 64 * j]; ss += v[j] * v[j]; }
#pragma unroll
  for (int m = 32; m >= 1; m >>= 1) ss += __shfl_xor(ss, m, 64);
  float nrm  = sqrtf(ss);
  float inv1 = 1.f / fmaxf(nrm, 1e-12f);
  float inv2 = 1.f / fmaxf(nrm * inv1, 1e-8f);
#pragma unroll
  for (int j = 0; j < 4; ++j) {
    float e1 = v[j] * inv1;
    E1[(size_t)row * H_DIM + lane + 64 * j] = e1;
    En[(size_t)row * H_DIM + lane + 64 * j] = e1 * inv2;
  }
}

__global__ void k_cent(const float* __restrict__ E1, float* __restrict__ C,
                       float* __restrict__ CnT) {
  int n = blockIdx.x;
  int lane = threadIdx.x;  // 64
  float v[4]; float ss = 0.f;
#pragma unroll
  for (int j = 0; j < 4; ++j) {
    int col = lane + 64 * j;
    float s = 0.f;
    for (int m = 0; m < M_UTT; ++m) s += E1[((size_t)n * M_UTT + m) * H_DIM + col];
    v[j] = s / (float)M_UTT;
    ss += v[j] * v[j];
  }
#pragma unroll
  for (int m = 32; m >= 1; m >>= 1) ss += __shfl_xor(ss, m, 64);
  float inv = 1.f / fmaxf(sqrtf(ss), 1e-8f);
#pragma unroll
  for (int j = 0; j < 4; ++j) {
    int col = lane + 64 * j;
    C[(size_t)n * H_DIM + col]  = v[j];
    CnT[(size_t)col * N_SPK + n] = v[j] * inv;
  }
}

__global__ void k_cm(const float* __restrict__ E1, const float* __restrict__ C,
                     float* __restrict__ Cmn) {
  int b    = blockIdx.x * 4 + (threadIdx.x >> 6);
  int lane = threadIdx.x & 63;
  int spk  = b / M_UTT;
  float v[4]; float ss = 0.f;
#pragma unroll
  for (int j = 0; j < 4; ++j) {
    int col = lane + 64 * j;
    v[j] = ((float)M_UTT * C[(size_t)spk * H_DIM + col] + E1[(size_t)b * H_DIM + col])
           / (float)(M_UTT - 1);
    ss += v[j] * v[j];
  }
#pragma unroll
  for (int m = 32; m >= 1; m >>= 1) ss += __shfl_xor(ss, m, 64);
  float inv = 1.f / fmaxf(sqrtf(ss), 1e-8f);
#pragma unroll
  for (int j = 0; j < 4; ++j)
    Cmn[(size_t)b * H_DIM + lane + 64 * j] = v[j] * inv;
}

__global__ void k_sim(const float* __restrict__ En, const float* __restrict__ CnT,
                      const float* __restrict__ Cmn, const float* __restrict__ w_sim,
                      const float* __restrict__ b_sim, float* __restrict__ S) {
  int b = blockIdx.x;
  int n = threadIdx.x;  // 64
  int diag = b / M_UTT;
  float w = w_sim[0], bb = b_sim[0];
  float s = 0.f;
  for (int k = 0; k < H_DIM; ++k) {
    float en = En[(size_t)b * H_DIM + k];
    float c  = (n == diag) ? Cmn[(size_t)b * H_DIM + k] : CnT[(size_t)k * N_SPK + n];
    s += en * c;
  }
  S[(size_t)b * N_SPK + n] = s * w + bb;
}

// ---------------------------------------------------------------------------
// Workspace layout (bytes). Fixed part then runtime-sized G chunk (verified R3).
// ---------------------------------------------------------------------------
#define O_WHH   0ull
#define O_WIH0  1572864ull
#define O_WIH1  1703936ull
#define O_WIH2  2228224ull
#define O_BIAS  2752512ull
#define O_CST   2764800ull      // fp32 c state; aliases E at the end
#define O_HST   3420160ull
#define O_HSEQ  3747840ull
#define O_G     56176640ull     // TC * 1310720

extern "C" void kernel_launch(void* const* d_in, const int* in_sizes, int n_in,
                              void* d_out, int out_size, void* d_ws, size_t ws_size,
                              hipStream_t stream) {
  const float* seq   = (const float*)d_in[0];
  const int*   lens  = (const int*)d_in[1];
  const float* w_sim = (const float*)d_in[2];
  const float* b_sim = (const float*)d_in[3];
  const float* Wih[3] = {(const float*)d_in[4],  (const float*)d_in[8],  (const float*)d_in[12]};
  const float* Whh[3] = {(const float*)d_in[5],  (const float*)d_in[9],  (const float*)d_in[13]};
  const float* bih[3] = {(const float*)d_in[6],  (const float*)d_in[10], (const float*)d_in[14]};
  const float* bhh[3] = {(const float*)d_in[7],  (const float*)d_in[11], (const float*)d_in[15]};

  char* ws = (char*)d_ws;
  short* Whhp[3] = {(short*)(ws + O_WHH), (short*)(ws + O_WHH + 524288),
                    (short*)(ws + O_WHH + 1048576)};
  short* Wihp[3] = {(short*)(ws + O_WIH0), (short*)(ws + O_WIH1), (short*)(ws + O_WIH2)};
  float* biasc = (float*)(ws + O_BIAS);
  float* c_state = (float*)(ws + O_CST);
  unsigned short* h_state = (unsigned short*)(ws + O_HST);
  unsigned short* hseq = (unsigned short*)(ws + O_HSEQ);
  unsigned short* G    = (unsigned short*)(ws + O_G);
  float* E1  = (float*)(ws + O_G);
  float* En  = (float*)(ws + O_G + 655360);
  float* C   = (float*)(ws + O_G + 1310720);
  float* CnT = (float*)(ws + O_G + 1376256);
  float* Cmn = (float*)(ws + O_G + 1441792);
  float* S   = (float*)d_out;

  const size_t base = O_G, per4 = 4ull * 40 * 64 * 256 * 2;
  int units = (ws_size > base) ? (int)((ws_size - base) / per4) : 0;
  int TC = units * 4;
  if (TC > T_SEQ) TC = T_SEQ;
  if (TC < 4) TC = 4;

  pack_w_kernel<<<32, 256, 0, stream>>>(Wih[0], Wihp[0], IN_F, 2);
  pack_w_kernel<<<128, 256, 0, stream>>>(Whh[0], Whhp[0], H_DIM, 8);
  pack_w_kernel<<<128, 256, 0, stream>>>(Wih[1], Wihp[1], H_DIM, 8);
  pack_w_kernel<<<128, 256, 0, stream>>>(Whh[1], Whhp[1], H_DIM, 8);
  pack_w_kernel<<<128, 256, 0, stream>>>(Wih[2], Wihp[2], H_DIM, 8);
  pack_w_kernel<<<128, 256, 0, stream>>>(Whh[2], Whhp[2], H_DIM, 8);
  for (int l = 0; l < 3; ++l)
    bias_sum_kernel<<<4, 256, 0, stream>>>(bih[l], bhh[l], biasc + l * G4);

  for (int l = 0; l < 3; ++l) {
    hipMemsetAsync(c_state, 0, 655360, stream);
    hipMemsetAsync(h_state, 0, 327680, stream);
    for (int t0 = 0; t0 < T_SEQ; t0 += TC) {
      int steps = T_SEQ - t0; if (steps > TC) steps = TC;
      int ggrid = 40 * (steps / 4);
      if (l == 0)
        gate_gemm<2, 1><<<ggrid, 256, 0, stream>>>(seq, nullptr, Wihp[0], biasc, G, t0);
      else
        gate_gemm<8, 0><<<ggrid, 256, 0, stream>>>(nullptr, hseq, Wihp[l], biasc + l * G4, G, t0);
      if (l < 2)
        lstm_rec<1><<<40, 512, 0, stream>>>(Whhp[l], G, lens, hseq, h_state, c_state, t0, t0 + steps);
      else
        lstm_rec<0><<<40, 512, 0, stream>>>(Whhp[l], G, lens, nullptr, h_state, c_state, t0, t0 + steps);
    }
  }

  k_norm<<<160, 256, 0, stream>>>(c_state, E1, En);
  k_cent<<<N_SPK, 64, 0, stream>>>(E1, C, CnT);
  k_cm<<<160, 256, 0, stream>>>(E1, C, Cmn);
  k_sim<<<B_TOT, 64, 0, stream>>>(En, CnT, Cmn, w_sim, b_sim, S);
}